// Round 1
// baseline (108.784 us; speedup 1.0000x reference)
//
#include <hip/hip_runtime.h>
#include <math.h>

#define HF 96
#define WF 192
#define CC 32
#define NPIX (HF*WF)     // 18432
#define DFULL 192
#define DQ 48
#define HO 384
#define WO 768
#define SR 200           // R row stride in LDS: 4 zero-guard floats + 192 + 4 pad

// Cost volume, fused L2 norm, 4x4 (w,d) register tiles.
// Grid (96 rows, 5 tile-chunks), 256 threads. Tiles enumerated so consecutive
// threads share dt and ascend wt -> b128 LDS reads stride 16B (conflict-free)
// and float4 stores coalesce. Zero guard Rb[c][0..3]=0 makes diagonal tiles'
// w<d outputs exactly 0; strict-upper tiles zero-filled by mirror threads.
__global__ __launch_bounds__(256) void kcost(const float* __restrict__ L,
                                             const float* __restrict__ R,
                                             float* __restrict__ out) {
    __shared__ __align__(16) float Ls[CC * WF];   // 24.0 KB, Lnorm[c][w]
    __shared__ __align__(16) float Rb[CC * SR];   // 25.0 KB, Rnorm[c][w-4] (guarded)
    const int h = blockIdx.x;
    const int tid = threadIdx.x;

    // zero guard at head of each R row
    for (int i = tid; i < CC * 4; i += 256) Rb[(i >> 2) * SR + (i & 3)] = 0.0f;

    if (tid < WF) {
        const int w = tid;
        float lr[CC], rr[CC];
        float sl = 0.0f, sr = 0.0f;
        #pragma unroll
        for (int c = 0; c < CC; ++c) {
            float lv = L[c * NPIX + h * WF + w];
            float rv = R[c * NPIX + h * WF + w];
            lr[c] = lv; rr[c] = rv;
            sl = fmaf(lv, lv, sl);
            sr = fmaf(rv, rv, sr);
        }
        const float il = 1.0f / sqrtf(sl + 1e-12f);
        const float ir = 1.0f / sqrtf(sr + 1e-12f);
        #pragma unroll
        for (int c = 0; c < CC; ++c) {
            Ls[c * WF + w] = lr[c] * il;
            Rb[c * SR + 4 + w] = rr[c] * ir;
        }
    }
    __syncthreads();

    const int t = blockIdx.y * 256 + tid;
    if (t >= 1176) return;

    // reversed-triangle decode: u=1175-t -> (wu,du) lower-tri; wt=47-du, dt=47-wu
    // => consecutive t: same dt, wt ascending.
    const int u = 1175 - t;
    int wu = (int)((sqrtf(8.0f * (float)u + 1.0f) - 1.0f) * 0.5f);
    while ((wu + 1) * (wu + 2) / 2 <= u) ++wu;
    while (wu * (wu + 1) / 2 > u) --wu;
    const int du = u - wu * (wu + 1) / 2;
    const int wt = 47 - du;
    const int dt = 47 - wu;

    const int w0 = wt * 4, d0 = dt * 4;
    const int base = w0 - d0;           // >= 0, multiple of 4

    float a00=0,a01=0,a02=0,a03=0;      // a[j][i], j = d offset, i = w offset
    float a10=0,a11=0,a12=0,a13=0;
    float a20=0,a21=0,a22=0,a23=0;
    float a30=0,a31=0,a32=0,a33=0;

    #pragma unroll 4
    for (int c = 0; c < CC; ++c) {
        const float4 lv = *(const float4*)&Ls[c * WF + w0];
        const float4 r0 = *(const float4*)&Rb[c * SR + base];      // Rn[base-4..base-1]
        const float4 r1 = *(const float4*)&Rb[c * SR + base + 4];  // Rn[base..base+3]
        // output (i,j) uses Rn[base + i - j]
        a00 = fmaf(lv.x, r1.x, a00); a01 = fmaf(lv.y, r1.y, a01);
        a02 = fmaf(lv.z, r1.z, a02); a03 = fmaf(lv.w, r1.w, a03);
        a10 = fmaf(lv.x, r0.w, a10); a11 = fmaf(lv.y, r1.x, a11);
        a12 = fmaf(lv.z, r1.y, a12); a13 = fmaf(lv.w, r1.z, a13);
        a20 = fmaf(lv.x, r0.z, a20); a21 = fmaf(lv.y, r0.w, a21);
        a22 = fmaf(lv.z, r1.x, a22); a23 = fmaf(lv.w, r1.y, a23);
        a30 = fmaf(lv.x, r0.y, a30); a31 = fmaf(lv.y, r0.z, a31);
        a32 = fmaf(lv.z, r0.w, a32); a33 = fmaf(lv.w, r1.x, a33);
    }

    {
        float4 v;
        v.x=a00; v.y=a01; v.z=a02; v.w=a03;
        *(float4*)&out[(d0 + 0) * NPIX + h * WF + w0] = v;
        v.x=a10; v.y=a11; v.z=a12; v.w=a13;
        *(float4*)&out[(d0 + 1) * NPIX + h * WF + w0] = v;
        v.x=a20; v.y=a21; v.z=a22; v.w=a23;
        *(float4*)&out[(d0 + 2) * NPIX + h * WF + w0] = v;
        v.x=a30; v.y=a31; v.z=a32; v.w=a33;
        *(float4*)&out[(d0 + 3) * NPIX + h * WF + w0] = v;
    }

    if (wt > dt) {
        // zero the mirrored strict-upper tile: a = wt-dt-1, b = 47-dt (a < b)
        const int za = (wt - dt - 1) * 4;
        const int zb = (47 - dt) * 4;
        const float4 z = {0.0f, 0.0f, 0.0f, 0.0f};
        #pragma unroll
        for (int j = 0; j < 4; ++j)
            *(float4*)&out[(zb + j) * NPIX + h * WF + za] = z;
    }
}

// Trilinear upsample + argmax, v2.
// Compact grid (3, HF) x (64,4): mIdx = 0..191, zero dead threads.
//   mIdx=0   -> m=-1: left edge (w_out 0,1), fr=0 path (exactly original).
//   mIdx=1.. -> m=0..190 interior: 4 outputs {4m+2..4m+5} share cols (m,m+1).
//   m=190 additionally carries the right-edge chain (w_out 766,767 = col 191):
//   its A1 is bitwise-identical to the original edge thread's A0 (same
//   addresses, same fmaf order), tracked branchlessly for all lanes (~7 VALU/k).
// k-loop fully unrolled so all 188 loads can be hoisted ahead of the serial
// compare chain -> latency hidden at low occupancy (1.5 waves/SIMD).
__global__ __launch_bounds__(256) void kpred(const float* __restrict__ cost,
                                             float* __restrict__ pred) {
    const int mIdx = blockIdx.x * 64 + threadIdx.x;  // 0..191, all valid
    const int h = blockIdx.y * 4 + threadIdx.y;
    const int m = mIdx - 1;                          // -1..190

    float sh = (float)(2 * h - 3) * 0.125f;
    float fh = sh - floorf(sh);
    int h0 = (int)floorf(sh);
    int h1 = h0 + 1;
    if (h0 < 0)      { h0 = 0; h1 = 0; fh = 0.0f; }
    if (h1 > HF - 1) { h1 = HF - 1;    fh = 0.0f; }
    const float wh0 = 1.0f - fh, wh1 = fh;

    const bool leftE = (m < 0);
    const bool rightE = (m == WF - 2);               // m == 190
    const int w0 = leftE ? 0 : m;
    const int w1 = leftE ? 0 : m + 1;

    float fr[4];
    #pragma unroll
    for (int r = 0; r < 4; ++r) fr[r] = leftE ? 0.0f : (0.125f + 0.25f * (float)r);

    const float* p00 = cost + h0 * WF + w0;
    const float* p10 = cost + h1 * WF + w0;
    const float* p01 = cost + h0 * WF + w1;
    const float* p11 = cost + h1 * WF + w1;

    float bp[4], best[4];
    int bi[4];
    float bpR, bestR;
    int biR;
    {
        float q00 = p00[0], q10 = p10[0], q01 = p01[0], q11 = p11[0];
        float A0 = fmaf(wh1, q10, wh0 * q00);
        float A1 = fmaf(wh1, q11, wh0 * q01);
        #pragma unroll
        for (int r = 0; r < 4; ++r) {
            bp[r] = fmaf(fr[r], A1, (1.0f - fr[r]) * A0);
            best[r] = bp[r];
            bi[r] = 0;
        }
        bpR = A1; bestR = A1; biR = 0;
    }

    #pragma unroll
    for (int k = 1; k < DQ; ++k) {
        const int off = k * NPIX;
        float q00 = p00[off], q10 = p10[off], q01 = p01[off], q11 = p11[off];
        float A0 = fmaf(wh1, q10, wh0 * q00);
        float A1 = fmaf(wh1, q11, wh0 * q01);
        #pragma unroll
        for (int r = 0; r < 4; ++r) {
            float b = fmaf(fr[r], A1, (1.0f - fr[r]) * A0);
            float cand; int ci;
            if (b > bp[r]) { cand = fmaf(0.875f, b, 0.125f * bp[r]); ci = 4 * k + 1; }
            else           { cand = fmaf(0.125f, b, 0.875f * bp[r]); ci = 4 * k - 2; }
            if (cand > best[r]) { best[r] = cand; bi[r] = ci; }
            bp[r] = b;
        }
        {   // right-edge chain on A1 (only consumed when rightE)
            float b = A1;
            float cand; int ci;
            if (b > bpR) { cand = fmaf(0.875f, b, 0.125f * bpR); ci = 4 * k + 1; }
            else         { cand = fmaf(0.125f, b, 0.875f * bpR); ci = 4 * k - 2; }
            if (cand > bestR) { bestR = cand; biR = ci; }
            bpR = b;
        }
    }
    #pragma unroll
    for (int r = 0; r < 4; ++r)
        if (bp[r] > best[r]) bi[r] = 190;      // d_out = 190,191 fold to slice 47
    if (bpR > bestR) biR = 190;

    float v[4];
    #pragma unroll
    for (int r = 0; r < 4; ++r) v[r] = (float)(bi[r] < 1 ? 1 : bi[r]);
    const float vR = (float)(biR < 1 ? 1 : biR);

    float* prow = pred + h * WO;
    if (leftE) {
        float2 o; o.x = v[0]; o.y = v[0];
        *(float2*)&prow[0] = o;                 // w_out 0,1 = col 0
    } else {
        float2 o0; o0.x = v[0]; o0.y = v[1];
        float2 o1; o1.x = v[2]; o1.y = v[3];
        *(float2*)&prow[4 * m + 2] = o0;
        *(float2*)&prow[4 * m + 4] = o1;
        if (rightE) {
            float2 o; o.x = vR; o.y = vR;
            *(float2*)&prow[WO - 2] = o;        // w_out 766,767 = col 191
        }
    }
}

extern "C" void kernel_launch(void* const* d_in, const int* in_sizes, int n_in,
                              void* d_out, int out_size, void* d_ws, size_t ws_size,
                              hipStream_t stream) {
    const float* L = (const float*)d_in[0];
    const float* R = (const float*)d_in[1];
    float* out = (float*)d_out;                 // cost_init: [192][96][192]
    float* pred = out + DFULL * NPIX;           // pred: [384][768]

    kcost<<<dim3(HF, 5), 256, 0, stream>>>(L, R, out);
    kpred<<<dim3(3, HF), dim3(64, 4), 0, stream>>>(out, pred);
}

// Round 2
// 97.559 us; speedup vs baseline: 1.1151x; 1.1151x over previous
//
#include <hip/hip_runtime.h>
#include <math.h>

#define HF 96
#define WF 192
#define CC 32
#define NPIX (HF*WF)     // 18432
#define DFULL 192
#define DQ 48
#define HO 384
#define WO 768
#define SR 200           // R row stride in LDS: 4 zero-guard floats + 192 + 4 pad

// Cost volume, fused L2 norm, 4x4 (w,d) register tiles.
// Grid (96 rows, 5 tile-chunks), 256 threads. Tiles enumerated so consecutive
// threads share dt and ascend wt -> b128 LDS reads stride 16B (conflict-free)
// and float4 stores coalesce. Zero guard Rb[c][0..3]=0 makes diagonal tiles'
// w<d outputs exactly 0; strict-upper tiles zero-filled by mirror threads.
__global__ __launch_bounds__(256) void kcost(const float* __restrict__ L,
                                             const float* __restrict__ R,
                                             float* __restrict__ out) {
    __shared__ __align__(16) float Ls[CC * WF];   // 24.0 KB, Lnorm[c][w]
    __shared__ __align__(16) float Rb[CC * SR];   // 25.0 KB, Rnorm[c][w-4] (guarded)
    const int h = blockIdx.x;
    const int tid = threadIdx.x;

    // zero guard at head of each R row
    for (int i = tid; i < CC * 4; i += 256) Rb[(i >> 2) * SR + (i & 3)] = 0.0f;

    if (tid < WF) {
        const int w = tid;
        float lr[CC], rr[CC];
        float sl = 0.0f, sr = 0.0f;
        #pragma unroll
        for (int c = 0; c < CC; ++c) {
            float lv = L[c * NPIX + h * WF + w];
            float rv = R[c * NPIX + h * WF + w];
            lr[c] = lv; rr[c] = rv;
            sl = fmaf(lv, lv, sl);
            sr = fmaf(rv, rv, sr);
        }
        const float il = 1.0f / sqrtf(sl + 1e-12f);
        const float ir = 1.0f / sqrtf(sr + 1e-12f);
        #pragma unroll
        for (int c = 0; c < CC; ++c) {
            Ls[c * WF + w] = lr[c] * il;
            Rb[c * SR + 4 + w] = rr[c] * ir;
        }
    }
    __syncthreads();

    const int t = blockIdx.y * 256 + tid;
    if (t >= 1176) return;

    // reversed-triangle decode: u=1175-t -> (wu,du) lower-tri; wt=47-du, dt=47-wu
    // => consecutive t: same dt, wt ascending.
    const int u = 1175 - t;
    int wu = (int)((sqrtf(8.0f * (float)u + 1.0f) - 1.0f) * 0.5f);
    while ((wu + 1) * (wu + 2) / 2 <= u) ++wu;
    while (wu * (wu + 1) / 2 > u) --wu;
    const int du = u - wu * (wu + 1) / 2;
    const int wt = 47 - du;
    const int dt = 47 - wu;

    const int w0 = wt * 4, d0 = dt * 4;
    const int base = w0 - d0;           // >= 0, multiple of 4

    float a00=0,a01=0,a02=0,a03=0;      // a[j][i], j = d offset, i = w offset
    float a10=0,a11=0,a12=0,a13=0;
    float a20=0,a21=0,a22=0,a23=0;
    float a30=0,a31=0,a32=0,a33=0;

    #pragma unroll 4
    for (int c = 0; c < CC; ++c) {
        const float4 lv = *(const float4*)&Ls[c * WF + w0];
        const float4 r0 = *(const float4*)&Rb[c * SR + base];      // Rn[base-4..base-1]
        const float4 r1 = *(const float4*)&Rb[c * SR + base + 4];  // Rn[base..base+3]
        // output (i,j) uses Rn[base + i - j]
        a00 = fmaf(lv.x, r1.x, a00); a01 = fmaf(lv.y, r1.y, a01);
        a02 = fmaf(lv.z, r1.z, a02); a03 = fmaf(lv.w, r1.w, a03);
        a10 = fmaf(lv.x, r0.w, a10); a11 = fmaf(lv.y, r1.x, a11);
        a12 = fmaf(lv.z, r1.y, a12); a13 = fmaf(lv.w, r1.z, a13);
        a20 = fmaf(lv.x, r0.z, a20); a21 = fmaf(lv.y, r0.w, a21);
        a22 = fmaf(lv.z, r1.x, a22); a23 = fmaf(lv.w, r1.y, a23);
        a30 = fmaf(lv.x, r0.y, a30); a31 = fmaf(lv.y, r0.z, a31);
        a32 = fmaf(lv.z, r0.w, a32); a33 = fmaf(lv.w, r1.x, a33);
    }

    {
        float4 v;
        v.x=a00; v.y=a01; v.z=a02; v.w=a03;
        *(float4*)&out[(d0 + 0) * NPIX + h * WF + w0] = v;
        v.x=a10; v.y=a11; v.z=a12; v.w=a13;
        *(float4*)&out[(d0 + 1) * NPIX + h * WF + w0] = v;
        v.x=a20; v.y=a21; v.z=a22; v.w=a23;
        *(float4*)&out[(d0 + 2) * NPIX + h * WF + w0] = v;
        v.x=a30; v.y=a31; v.z=a32; v.w=a33;
        *(float4*)&out[(d0 + 3) * NPIX + h * WF + w0] = v;
    }

    if (wt > dt) {
        // zero the mirrored strict-upper tile: a = wt-dt-1, b = 47-dt (a < b)
        const int za = (wt - dt - 1) * 4;
        const int zb = (47 - dt) * 4;
        const float4 z = {0.0f, 0.0f, 0.0f, 0.0f};
        #pragma unroll
        for (int j = 0; j < 4; ++j)
            *(float4*)&out[(zb + j) * NPIX + h * WF + za] = z;
    }
}

// Trilinear upsample + argmax, v3: lane-parallel argmax chain.
// The sequential segment-max recurrence is associative: candidate k's value
// depends only on samples b[k-1], b[k]; sequential strict-> update == argmax
// with smallest-candidate-index tie-break (indices 4k-2/4k+1 strictly increase
// in evaluation order; the final b47->190 check is strict-> with the largest
// index). So: 8 lanes per (h_out, mIdx) chain; lane j owns k in [6j+1, 6j+6]
// (lane 7: 43..47 plus the 190-candidate), loads its 7 needed samples (28
// independent L2-hot loads, fully pipelined), runs the bit-identical fmaf
// chain locally, then 3-step __shfl_xor(width=8) max-reduce with
// (value, smaller-index-on-tie). 74112 chains * 8 lanes = 9264 waves
// (~9/SIMD) vs round-0's 1536 (1.5/SIMD): latency hidden, depth 48 -> 6+3.
__global__ __launch_bounds__(256) void kpred(const float* __restrict__ cost,
                                             float* __restrict__ pred) {
    const int tid = threadIdx.x;
    const int lane = tid & 7;
    const int chainId = blockIdx.x * 32 + (tid >> 3);   // < 74112 = 384*193
    const int h = chainId / 193;                        // h_out 0..383
    const int mIdx = chainId - h * 193;                 // 0..192
    const int m = mIdx - 1;                             // -1..191

    float sh = (float)(2 * h - 3) * 0.125f;
    float fh = sh - floorf(sh);
    int h0 = (int)floorf(sh);
    int h1 = h0 + 1;
    if (h0 < 0)      { h0 = 0; h1 = 0; fh = 0.0f; }
    if (h1 > HF - 1) { h1 = HF - 1;    fh = 0.0f; }
    const float wh0 = 1.0f - fh, wh1 = fh;

    const bool edge = (m < 0) || (m >= WF - 1);
    const int w0 = (m < 0) ? 0 : ((m >= WF - 1) ? WF - 1 : m);
    const int w1 = (m < 0) ? 0 : ((m >= WF - 1) ? WF - 1 : m + 1);

    float fr[4];
    #pragma unroll
    for (int r = 0; r < 4; ++r) fr[r] = edge ? 0.0f : (0.125f + 0.25f * (float)r);

    const int i00 = h0 * WF + w0;
    const int i10 = h1 * WF + w0;
    const int i01 = h0 * WF + w1;
    const int i11 = h1 * WF + w1;

    // lane j covers samples 6j .. 6j+6 (lane 7's sample 48 clamps to 47;
    // identical address -> identical value, candidate k=48 is masked off)
    const int base = 6 * lane;
    float A0v[7], A1v[7];
    #pragma unroll
    for (int t = 0; t < 7; ++t) {
        int s = base + t;
        if (s > 47) s = 47;
        const float* sp = cost + s * NPIX;
        const float q00 = sp[i00], q10 = sp[i10], q01 = sp[i01], q11 = sp[i11];
        A0v[t] = fmaf(wh1, q10, wh0 * q00);
        A1v[t] = fmaf(wh1, q11, wh0 * q01);
    }

    float bp[4], best[4];
    int bi[4];
    #pragma unroll
    for (int r = 0; r < 4; ++r) {
        const float b0 = fmaf(fr[r], A1v[0], (1.0f - fr[r]) * A0v[0]);
        bp[r] = b0;
        if (lane == 0) { best[r] = b0;        bi[r] = 0; }
        else           { best[r] = -INFINITY; bi[r] = 0x7fffffff; }
    }

    #pragma unroll
    for (int t = 1; t < 7; ++t) {
        const int k = base + t;
        const bool valid = (k <= 47);           // false only for lane 7, t=6
        #pragma unroll
        for (int r = 0; r < 4; ++r) {
            const float b = fmaf(fr[r], A1v[t], (1.0f - fr[r]) * A0v[t]);
            float cand; int ci;
            if (b > bp[r]) { cand = fmaf(0.875f, b, 0.125f * bp[r]); ci = 4 * k + 1; }
            else           { cand = fmaf(0.125f, b, 0.875f * bp[r]); ci = 4 * k - 2; }
            if (valid && cand > best[r]) { best[r] = cand; bi[r] = ci; }
            bp[r] = b;                          // clamped sample keeps bp == b47
        }
    }

    if (lane == 7) {
        // trailing candidate (b_47, 190): strict->, largest index -> ties lose,
        // exactly the sequential "if (bp > best) bi = 190" semantics.
        #pragma unroll
        for (int r = 0; r < 4; ++r)
            if (bp[r] > best[r]) { best[r] = bp[r]; bi[r] = 190; }
    }

    // butterfly max-reduce over the 8-lane group; smaller index wins ties
    #pragma unroll
    for (int mask = 1; mask < 8; mask <<= 1) {
        #pragma unroll
        for (int r = 0; r < 4; ++r) {
            const float ov = __shfl_xor(best[r], mask, 8);
            const int   oi = __shfl_xor(bi[r],   mask, 8);
            if (ov > best[r] || (ov == best[r] && oi < bi[r])) {
                best[r] = ov; bi[r] = oi;
            }
        }
    }

    if (lane != 0) return;

    float v[4];
    #pragma unroll
    for (int r = 0; r < 4; ++r) v[r] = (float)(bi[r] < 1 ? 1 : bi[r]);

    float* prow = pred + h * WO;
    if (m < 0) {
        float2 o; o.x = v[0]; o.y = v[0];
        *(float2*)&prow[0] = o;                 // w_out 0,1 = col 0
    } else if (m >= WF - 1) {
        float2 o; o.x = v[0]; o.y = v[0];
        *(float2*)&prow[WO - 2] = o;            // w_out 766,767 = col 191
    } else {
        float2 o0; o0.x = v[0]; o0.y = v[1];
        float2 o1; o1.x = v[2]; o1.y = v[3];
        *(float2*)&prow[4 * m + 2] = o0;
        *(float2*)&prow[4 * m + 4] = o1;
    }
}

extern "C" void kernel_launch(void* const* d_in, const int* in_sizes, int n_in,
                              void* d_out, int out_size, void* d_ws, size_t ws_size,
                              hipStream_t stream) {
    const float* L = (const float*)d_in[0];
    const float* R = (const float*)d_in[1];
    float* out = (float*)d_out;                 // cost_init: [192][96][192]
    float* pred = out + DFULL * NPIX;           // pred: [384][768]

    kcost<<<dim3(HF, 5), 256, 0, stream>>>(L, R, out);
    kpred<<<dim3(2316), 256, 0, stream>>>(out, pred);   // 74112 chains * 8 lanes
}